// Round 2
// baseline (132.087 us; speedup 1.0000x reference)
//
#include <hip/hip_runtime.h>

// Problem constants (B=1)
constexpr int C = 32, H = 256, W = 512, K = 10;
constexpr int HW = H * W;               // 131072
constexpr float TEMP = 10000.0f;

// XCD-aware bijective swizzle: hardware assigns block b to XCD (b % 8)
// (round-robin dispatch). Remap so XCD x processes a CONTIGUOUS chunk of
// work ids -> each XCD's private 4MB L2 holds only its own 32-row band of
// the 16MB rhwc image (plus oy jitter margin ~ +/-10 rows: ~3.3MB, fits).
__device__ __forceinline__ int xcd_swizzle(int bid, int nwg) {
    // nwg is a multiple of 8 for both kernels (2048 / 1024)
    return (bid & 7) * (nwg >> 3) + (bid >> 3);
}

// -------- transpose right: CHW f32 -> HWC f32 (pixel-major) ---------------
// Swizzled identically so the producer XCD matches the consumer XCD band.
__global__ __launch_bounds__(256) void conv_right_hwc(
    const float* __restrict__ in, float* __restrict__ out)
{
    __shared__ float t[C][129];          // +1 pad
    const int wg = xcd_swizzle(blockIdx.x, gridDim.x);
    const int base = wg * 128;
    const int tid = threadIdx.x;
    #pragma unroll
    for (int i = 0; i < 4; ++i) {
        int lin = i * 256 + tid;         // [0,1024)
        int c = lin >> 5, pq = lin & 31;
        float4 v = *(const float4*)(in + c * HW + base + pq * 4);
        t[c][pq * 4 + 0] = v.x;
        t[c][pq * 4 + 1] = v.y;
        t[c][pq * 4 + 2] = v.z;
        t[c][pq * 4 + 3] = v.w;
    }
    __syncthreads();
    #pragma unroll
    for (int i = 0; i < 4; ++i) {
        int lin = i * 256 + tid;
        int px = lin >> 3, cq = lin & 7;
        float4 v;
        v.x = t[cq * 4 + 0][px];
        v.y = t[cq * 4 + 1][px];
        v.z = t[cq * 4 + 2][px];
        v.w = t[cq * 4 + 3][px];
        *(float4*)(out + (base + px) * C + cq * 4) = v;
    }
}

// -------- main: 4 lanes per pixel, 8 channels each, right in HWC ----------
// Streaming operands (left, offsets, out) use non-temporal hints so they
// don't evict the gather working set from the XCD-private L2.
__global__ __launch_bounds__(256, 4) void disp_kernel_hwc(
    const float* __restrict__ lchw, const float* __restrict__ rhwc,
    const float* __restrict__ offx, const float* __restrict__ offy,
    float* __restrict__ out)
{
    const int tid = threadIdx.x;
    const int q = tid & 3;                        // channel quarter
    const int wg = xcd_swizzle(blockIdx.x, gridDim.x);
    const int p = wg * 64 + (tid >> 2);           // pixel id
    const int w = p & (W - 1);
    const int h = p >> 9;

    // left features from CHW (streaming, single-use -> non-temporal)
    float lf[8];
    #pragma unroll
    for (int j = 0; j < 4; ++j)
        lf[j]     = __builtin_nontemporal_load(&lchw[(q * 4 + j) * HW + p]);
    #pragma unroll
    for (int j = 0; j < 4; ++j)
        lf[4 + j] = __builtin_nontemporal_load(&lchw[(16 + q * 4 + j) * HW + p]);

    // preload all K offsets (streaming -> non-temporal)
    float okx[K], oky[K];
    #pragma unroll
    for (int k = 0; k < K; ++k) {
        okx[k] = __builtin_nontemporal_load(&offx[k * HW + p]);
        oky[k] = __builtin_nontemporal_load(&offy[k * HW + p]);
    }

    const float lx = (float)w;
    const float ly = (float)h;   // ref clips y to W-1: no-op (H <= W)
    const float4* rbase = (const float4*)rhwc;   // 8 float4 per pixel

    float s[K];

    #pragma unroll
    for (int k = 0; k < K; ++k) {
        const float ox = okx[k];
        const float oy = oky[k];

        // mirror reference arithmetic exactly
        float rx = fminf(fmaxf(lx - ox, 0.0f), (float)(W - 1));
        float ry = fminf(fmaxf(ly - oy, 0.0f), (float)(H - 1));
        float gx = (rx - (float)(W / 2)) / (float)(W / 2);
        float gy = (ry - (float)(H / 2)) / (float)(H / 2);
        float ix = ((gx + 1.0f) * (float)W - 1.0f) * 0.5f;
        float iy = ((gy + 1.0f) * (float)H - 1.0f) * 0.5f;

        float x0f = floorf(ix), y0f = floorf(iy);
        float wx1 = ix - x0f, wy1 = iy - y0f;
        float wx0 = 1.0f - wx1, wy0 = 1.0f - wy1;
        int x0 = (int)x0f, y0 = (int)y0f;
        int x1 = x0 + 1,  y1 = y0 + 1;

        float vx0 = (x0 >= 0 && x0 <= W - 1) ? 1.0f : 0.0f;
        float vx1 = (x1 >= 0 && x1 <= W - 1) ? 1.0f : 0.0f;
        float vy0 = (y0 >= 0 && y0 <= H - 1) ? 1.0f : 0.0f;
        float vy1 = (y1 >= 0 && y1 <= H - 1) ? 1.0f : 0.0f;
        float w00 = wx0 * wy0 * vx0 * vy0;
        float w01 = wx1 * wy0 * vx1 * vy0;
        float w10 = wx0 * wy1 * vx0 * vy1;
        float w11 = wx1 * wy1 * vx1 * vy1;

        int xi0 = min(max(x0, 0), W - 1), xi1 = min(max(x1, 0), W - 1);
        int yi0 = min(max(y0, 0), H - 1), yi1 = min(max(y1, 0), H - 1);

        int c00 = (yi0 * W + xi0) * 8;   // float4 index of record base
        int c01 = (yi0 * W + xi1) * 8;
        int c10 = (yi1 * W + xi0) * 8;
        int c11 = (yi1 * W + xi1) * 8;
        float4 a0 = rbase[c00 + q], a1 = rbase[c00 + 4 + q];
        float4 b0 = rbase[c01 + q], b1 = rbase[c01 + 4 + q];
        float4 d0 = rbase[c10 + q], d1 = rbase[c10 + 4 + q];
        float4 e0 = rbase[c11 + q], e1 = rbase[c11 + 4 + q];
        float ca[8] = {a0.x, a0.y, a0.z, a0.w, a1.x, a1.y, a1.z, a1.w};
        float cb[8] = {b0.x, b0.y, b0.z, b0.w, b1.x, b1.y, b1.z, b1.w};
        float cd[8] = {d0.x, d0.y, d0.z, d0.w, d1.x, d1.y, d1.z, d1.w};
        float ce[8] = {e0.x, e0.y, e0.z, e0.w, e1.x, e1.y, e1.z, e1.w};

        float acc = 0.0f;
        #pragma unroll
        for (int j = 0; j < 8; ++j) {
            float g = w00 * ca[j] + w01 * cb[j] + w10 * cd[j] + w11 * ce[j];
            acc += fabsf(lf[j] - g);
        }
        // sum the 4 channel-quarter partials of this pixel group
        acc += __shfl_xor(acc, 1);
        acc += __shfl_xor(acc, 2);
        s[k] = acc * (-TEMP / (float)C);   // -312.5 exact
    }

    // softmax over K (redundant in all 4 lanes; lane q==0 writes)
    float m = s[0];
    #pragma unroll
    for (int k = 1; k < K; ++k) m = fmaxf(m, s[k]);
    float den = 0.0f, sx = 0.0f, sy = 0.0f;
    #pragma unroll
    for (int k = 0; k < K; ++k) {
        float e = __expf(s[k] - m);
        den += e;
        sx += okx[k] * e;
        sy += oky[k] * e;
    }
    float inv = 1.0f / den;
    if (q == 0) {
        __builtin_nontemporal_store(sx * inv, &out[p]);
        __builtin_nontemporal_store(sy * inv, &out[HW + p]);
    }
}

// -------- fallback (round-1 kernel) if workspace too small ----------------
__global__ __launch_bounds__(256) void disp_kernel_chw(
    const float* __restrict__ left, const float* __restrict__ right,
    const float* __restrict__ offx, const float* __restrict__ offy,
    float* __restrict__ out)
{
    const int p = blockIdx.x * 256 + threadIdx.x;
    const int w = p & (W - 1);
    const int h = p >> 9;
    float lf[C];
    #pragma unroll
    for (int c = 0; c < C; ++c) lf[c] = left[c * HW + p];
    const float lx = (float)w, ly = (float)h;
    float s[K], okx[K], oky[K];
    #pragma unroll
    for (int k = 0; k < K; ++k) {
        const float ox = offx[k * HW + p], oy = offy[k * HW + p];
        okx[k] = ox; oky[k] = oy;
        float rx = fminf(fmaxf(lx - ox, 0.0f), (float)(W - 1));
        float ry = fminf(fmaxf(ly - oy, 0.0f), (float)(H - 1));
        float gx = (rx - 256.0f) / 256.0f, gy = (ry - 128.0f) / 128.0f;
        float ix = ((gx + 1.0f) * (float)W - 1.0f) * 0.5f;
        float iy = ((gy + 1.0f) * (float)H - 1.0f) * 0.5f;
        float x0f = floorf(ix), y0f = floorf(iy);
        float wx1 = ix - x0f, wy1 = iy - y0f;
        float wx0 = 1.0f - wx1, wy0 = 1.0f - wy1;
        int x0 = (int)x0f, y0 = (int)y0f, x1 = x0 + 1, y1 = y0 + 1;
        float vx0 = (x0 >= 0 && x0 <= W - 1) ? 1.0f : 0.0f;
        float vx1 = (x1 >= 0 && x1 <= W - 1) ? 1.0f : 0.0f;
        float vy0 = (y0 >= 0 && y0 <= H - 1) ? 1.0f : 0.0f;
        float vy1 = (y1 >= 0 && y1 <= H - 1) ? 1.0f : 0.0f;
        float w00 = wx0 * wy0 * vx0 * vy0, w01 = wx1 * wy0 * vx1 * vy0;
        float w10 = wx0 * wy1 * vx0 * vy1, w11 = wx1 * wy1 * vx1 * vy1;
        int xi0 = min(max(x0, 0), W - 1), xi1 = min(max(x1, 0), W - 1);
        int yi0 = min(max(y0, 0), H - 1), yi1 = min(max(y1, 0), H - 1);
        int i00 = yi0 * W + xi0, i01 = yi0 * W + xi1;
        int i10 = yi1 * W + xi0, i11 = yi1 * W + xi1;
        float acc = 0.0f;
        #pragma unroll
        for (int c = 0; c < C; ++c) {
            const float* rc = right + c * HW;
            acc += fabsf(lf[c] - (w00 * rc[i00] + w01 * rc[i01]
                                + w10 * rc[i10] + w11 * rc[i11]));
        }
        s[k] = acc * (-TEMP / (float)C);
    }
    float m = s[0];
    #pragma unroll
    for (int k = 1; k < K; ++k) m = fmaxf(m, s[k]);
    float den = 0.0f, sx = 0.0f, sy = 0.0f;
    #pragma unroll
    for (int k = 0; k < K; ++k) {
        float e = __expf(s[k] - m);
        den += e; sx += okx[k] * e; sy += oky[k] * e;
    }
    float inv = 1.0f / den;
    out[p] = sx * inv;
    out[HW + p] = sy * inv;
}

extern "C" void kernel_launch(void* const* d_in, const int* in_sizes, int n_in,
                              void* d_out, int out_size, void* d_ws, size_t ws_size,
                              hipStream_t stream) {
    const float* left  = (const float*)d_in[0];
    const float* right = (const float*)d_in[1];
    const float* offx  = (const float*)d_in[2];
    const float* offy  = (const float*)d_in[3];
    float* out = (float*)d_out;

    const size_t need = (size_t)HW * C * sizeof(float);   // 16 MB
    if (ws_size >= need) {
        float* rhwc = (float*)d_ws;
        conv_right_hwc<<<HW / 128, 256, 0, stream>>>(right, rhwc);
        disp_kernel_hwc<<<HW / 64, 256, 0, stream>>>(left, rhwc, offx, offy, out);
    } else {
        disp_kernel_chw<<<HW / 256, 256, 0, stream>>>(left, right, offx, offy, out);
    }
}

// Round 5
// 116.583 us; speedup vs baseline: 1.1330x; 1.1330x over previous
//
#include <hip/hip_runtime.h>

// Problem constants (B=1)
constexpr int C = 32, H = 256, W = 512, K = 10;
constexpr int HW = H * W;               // 131072
constexpr float TEMP = 10000.0f;

// -------- transpose right: CHW f32 -> HWC f32 (pixel-major) ---------------
__global__ __launch_bounds__(256) void conv_right_hwc(
    const float* __restrict__ in, float* __restrict__ out)
{
    __shared__ float t[C][129];          // +1 pad
    const int base = blockIdx.x * 128;
    const int tid = threadIdx.x;
    #pragma unroll
    for (int i = 0; i < 4; ++i) {
        int lin = i * 256 + tid;         // [0,1024)
        int c = lin >> 5, pq = lin & 31;
        float4 v = *(const float4*)(in + c * HW + base + pq * 4);
        t[c][pq * 4 + 0] = v.x;
        t[c][pq * 4 + 1] = v.y;
        t[c][pq * 4 + 2] = v.z;
        t[c][pq * 4 + 3] = v.w;
    }
    __syncthreads();
    #pragma unroll
    for (int i = 0; i < 4; ++i) {
        int lin = i * 256 + tid;
        int px = lin >> 3, cq = lin & 7;
        float4 v;
        v.x = t[cq * 4 + 0][px];
        v.y = t[cq * 4 + 1][px];
        v.z = t[cq * 4 + 2][px];
        v.w = t[cq * 4 + 3][px];
        *(float4*)(out + (base + px) * C + cq * 4) = v;
    }
}

// Per-candidate coordinate/weight/index computation — mirrors the reference
// arithmetic EXACTLY (absmax 0.25 proven with this expression order).
struct Cand { float w00, w01, w10, w11; int c00, c01, c10, c11; };

__device__ __forceinline__ Cand cand_calc(float lx, float ly, float ox, float oy)
{
    float rx = fminf(fmaxf(lx - ox, 0.0f), (float)(W - 1));
    float ry = fminf(fmaxf(ly - oy, 0.0f), (float)(H - 1));
    float gx = (rx - (float)(W / 2)) / (float)(W / 2);
    float gy = (ry - (float)(H / 2)) / (float)(H / 2);
    float ix = ((gx + 1.0f) * (float)W - 1.0f) * 0.5f;
    float iy = ((gy + 1.0f) * (float)H - 1.0f) * 0.5f;

    float x0f = floorf(ix), y0f = floorf(iy);
    float wx1 = ix - x0f, wy1 = iy - y0f;
    float wx0 = 1.0f - wx1, wy0 = 1.0f - wy1;
    int x0 = (int)x0f, y0 = (int)y0f;
    int x1 = x0 + 1,  y1 = y0 + 1;

    float vx0 = (x0 >= 0 && x0 <= W - 1) ? 1.0f : 0.0f;
    float vx1 = (x1 >= 0 && x1 <= W - 1) ? 1.0f : 0.0f;
    float vy0 = (y0 >= 0 && y0 <= H - 1) ? 1.0f : 0.0f;
    float vy1 = (y1 >= 0 && y1 <= H - 1) ? 1.0f : 0.0f;

    Cand cd;
    cd.w00 = wx0 * wy0 * vx0 * vy0;
    cd.w01 = wx1 * wy0 * vx1 * vy0;
    cd.w10 = wx0 * wy1 * vx0 * vy1;
    cd.w11 = wx1 * wy1 * vx1 * vy1;

    int xi0 = min(max(x0, 0), W - 1), xi1 = min(max(x1, 0), W - 1);
    int yi0 = min(max(y0, 0), H - 1), yi1 = min(max(y1, 0), H - 1);
    cd.c00 = (yi0 * W + xi0) * 8;     // float4 index of 128B record base
    cd.c01 = (yi0 * W + xi1) * 8;
    cd.c10 = (yi1 * W + xi0) * 8;
    cd.c11 = (yi1 * W + xi1) * 8;
    return cd;
}

// component select with compile-time j (folds to a plain register use)
#define F4AT(v, j) ((j) == 0 ? (v).x : (j) == 1 ? (v).y : (j) == 2 ? (v).z : (v).w)

// Per-lane channel set: {4q..4q+3} (line 0 of record) U {16+4q..16+4q+3}
// (line 1). P[2i] holds the line-0 quad, P[2i+1] the line-1 quad of corner i.
#define LOADSET(P, cd)                                           \
    do {                                                         \
        P[0] = rb[(cd).c00 + q];  P[1] = rb[(cd).c00 + 4 + q];   \
        P[2] = rb[(cd).c01 + q];  P[3] = rb[(cd).c01 + 4 + q];   \
        P[4] = rb[(cd).c10 + q];  P[5] = rb[(cd).c10 + 4 + q];   \
        P[6] = rb[(cd).c11 + q];  P[7] = rb[(cd).c11 + 4 + q];   \
    } while (0)

// j=0..3 -> line-0 quad (lf[0..3] = ch 4q+j); j=4..7 -> line-1 quad
// (lf[4..7] = ch 16+4q+j). Matches LOADSET's register layout exactly.
#define CONSUME(P, WT, kk)                                       \
    do {                                                         \
        float acc = 0.0f;                                        \
        _Pragma("unroll")                                        \
        for (int j = 0; j < 8; ++j) {                            \
            float a = F4AT(P[(j >> 2)],     j & 3);              \
            float b = F4AT(P[2 + (j >> 2)], j & 3);              \
            float d = F4AT(P[4 + (j >> 2)], j & 3);              \
            float e = F4AT(P[6 + (j >> 2)], j & 3);              \
            float g = WT.w00 * a + WT.w01 * b                    \
                    + WT.w10 * d + WT.w11 * e;                   \
            acc += fabsf(lf[j] - g);                             \
        }                                                        \
        acc += __shfl_xor(acc, 1);                               \
        acc += __shfl_xor(acc, 2);                               \
        s[kk] = acc * (-TEMP / (float)C);                        \
    } while (0)

// -------- main: 4 lanes/pixel, 8 ch each, f32 HWC, 2-deep k-pipeline ------
__global__ __launch_bounds__(256, 3) void disp_kernel_hwc(
    const float* __restrict__ lchw, const float* __restrict__ rhwc,
    const float* __restrict__ offx, const float* __restrict__ offy,
    float* __restrict__ out)
{
    const int tid = threadIdx.x;
    const int q = tid & 3;                        // channel quarter
    const int p = blockIdx.x * 64 + (tid >> 2);   // pixel id
    const int w = p & (W - 1);
    const int h = p >> 9;

    // left features matching the per-lane channel set (round-1 proven map)
    float lf[8];
    #pragma unroll
    for (int j = 0; j < 4; ++j) lf[j]     = lchw[(q * 4 + j) * HW + p];
    #pragma unroll
    for (int j = 0; j < 4; ++j) lf[4 + j] = lchw[(16 + q * 4 + j) * HW + p];

    float okx[K], oky[K];
    #pragma unroll
    for (int k = 0; k < K; ++k) {
        okx[k] = offx[k * HW + p];
        oky[k] = offy[k * HW + p];
    }

    const float lx = (float)w;
    const float ly = (float)h;   // ref clips y to W-1: no-op (H <= W)
    const float4* rb = (const float4*)rhwc;   // 8 float4 per pixel

    float s[K];
    float4 P0[8], P1[8];        // ping-pong corner register sets
    Cand   W0, W1;

    W0 = cand_calc(lx, ly, okx[0], oky[0]);   // prologue: issue k=0
    LOADSET(P0, W0);

    #pragma unroll
    for (int k = 0; k < K; ++k) {
        if (k + 1 < K) {                      // issue k+1 into other set
            if ((k & 1) == 0) {
                W1 = cand_calc(lx, ly, okx[k + 1], oky[k + 1]);
                LOADSET(P1, W1);
            } else {
                W0 = cand_calc(lx, ly, okx[k + 1], oky[k + 1]);
                LOADSET(P0, W0);
            }
        }
        // consume current parity (its weights were NOT overwritten above)
        if ((k & 1) == 0) CONSUME(P0, W0, k); else CONSUME(P1, W1, k);
    }

    // softmax over K (redundant in all 4 lanes; lane q==0 writes)
    float m = s[0];
    #pragma unroll
    for (int k = 1; k < K; ++k) m = fmaxf(m, s[k]);
    float den = 0.0f, sx = 0.0f, sy = 0.0f;
    #pragma unroll
    for (int k = 0; k < K; ++k) {
        float e = __expf(s[k] - m);
        den += e;
        sx += okx[k] * e;
        sy += oky[k] * e;
    }
    float inv = 1.0f / den;
    if (q == 0) {
        out[p]      = sx * inv;
        out[HW + p] = sy * inv;
    }
}

// -------- fallback (round-1 kernel) if workspace too small ----------------
__global__ __launch_bounds__(256) void disp_kernel_chw(
    const float* __restrict__ left, const float* __restrict__ right,
    const float* __restrict__ offx, const float* __restrict__ offy,
    float* __restrict__ out)
{
    const int p = blockIdx.x * 256 + threadIdx.x;
    const int w = p & (W - 1);
    const int h = p >> 9;
    float lf[C];
    #pragma unroll
    for (int c = 0; c < C; ++c) lf[c] = left[c * HW + p];
    const float lx = (float)w, ly = (float)h;
    float s[K], okx[K], oky[K];
    #pragma unroll
    for (int k = 0; k < K; ++k) {
        const float ox = offx[k * HW + p], oy = offy[k * HW + p];
        okx[k] = ox; oky[k] = oy;
        Cand cd = cand_calc(lx, ly, ox, oy);
        int i00 = cd.c00 >> 3, i01 = cd.c01 >> 3;
        int i10 = cd.c10 >> 3, i11 = cd.c11 >> 3;
        float acc = 0.0f;
        #pragma unroll
        for (int c = 0; c < C; ++c) {
            const float* rc = right + c * HW;
            acc += fabsf(lf[c] - (cd.w00 * rc[i00] + cd.w01 * rc[i01]
                                + cd.w10 * rc[i10] + cd.w11 * rc[i11]));
        }
        s[k] = acc * (-TEMP / (float)C);
    }
    float m = s[0];
    #pragma unroll
    for (int k = 1; k < K; ++k) m = fmaxf(m, s[k]);
    float den = 0.0f, sx = 0.0f, sy = 0.0f;
    #pragma unroll
    for (int k = 0; k < K; ++k) {
        float e = __expf(s[k] - m);
        den += e; sx += okx[k] * e; sy += oky[k] * e;
    }
    float inv = 1.0f / den;
    out[p] = sx * inv;
    out[HW + p] = sy * inv;
}

extern "C" void kernel_launch(void* const* d_in, const int* in_sizes, int n_in,
                              void* d_out, int out_size, void* d_ws, size_t ws_size,
                              hipStream_t stream) {
    const float* left  = (const float*)d_in[0];
    const float* right = (const float*)d_in[1];
    const float* offx  = (const float*)d_in[2];
    const float* offy  = (const float*)d_in[3];
    float* out = (float*)d_out;

    const size_t need = (size_t)HW * C * sizeof(float);   // 16 MB
    if (ws_size >= need) {
        float* rhwc = (float*)d_ws;
        conv_right_hwc<<<HW / 128, 256, 0, stream>>>(right, rhwc);
        disp_kernel_hwc<<<HW / 64, 256, 0, stream>>>(left, rhwc, offx, offy, out);
    } else {
        disp_kernel_chw<<<HW / 256, 256, 0, stream>>>(left, right, offx, offy, out);
    }
}

// Round 6
// 111.785 us; speedup vs baseline: 1.1816x; 1.0429x over previous
//
#include <hip/hip_runtime.h>

// Problem constants (B=1)
constexpr int C = 32, H = 256, W = 512, K = 10;
constexpr int HW = H * W;               // 131072
constexpr float TEMP = 10000.0f;

// -------- transpose right: CHW f32 -> HWC f32 (pixel-major) ---------------
__global__ __launch_bounds__(256) void conv_right_hwc(
    const float* __restrict__ in, float* __restrict__ out)
{
    __shared__ float t[C][129];          // +1 pad
    const int base = blockIdx.x * 128;
    const int tid = threadIdx.x;
    #pragma unroll
    for (int i = 0; i < 4; ++i) {
        int lin = i * 256 + tid;         // [0,1024)
        int c = lin >> 5, pq = lin & 31;
        float4 v = *(const float4*)(in + c * HW + base + pq * 4);
        t[c][pq * 4 + 0] = v.x;
        t[c][pq * 4 + 1] = v.y;
        t[c][pq * 4 + 2] = v.z;
        t[c][pq * 4 + 3] = v.w;
    }
    __syncthreads();
    #pragma unroll
    for (int i = 0; i < 4; ++i) {
        int lin = i * 256 + tid;
        int px = lin >> 3, cq = lin & 7;
        float4 v;
        v.x = t[cq * 4 + 0][px];
        v.y = t[cq * 4 + 1][px];
        v.z = t[cq * 4 + 2][px];
        v.w = t[cq * 4 + 3][px];
        *(float4*)(out + (base + px) * C + cq * 4) = v;
    }
}

// Per-candidate coordinate/weight/index computation — mirrors the reference
// arithmetic EXACTLY (absmax 0.25 proven with this expression order).
struct Cand { float w00, w01, w10, w11; int c00, c01, c10, c11; };

__device__ __forceinline__ Cand cand_calc(float lx, float ly, float ox, float oy)
{
    float rx = fminf(fmaxf(lx - ox, 0.0f), (float)(W - 1));
    float ry = fminf(fmaxf(ly - oy, 0.0f), (float)(H - 1));
    float gx = (rx - (float)(W / 2)) / (float)(W / 2);
    float gy = (ry - (float)(H / 2)) / (float)(H / 2);
    float ix = ((gx + 1.0f) * (float)W - 1.0f) * 0.5f;
    float iy = ((gy + 1.0f) * (float)H - 1.0f) * 0.5f;

    float x0f = floorf(ix), y0f = floorf(iy);
    float wx1 = ix - x0f, wy1 = iy - y0f;
    float wx0 = 1.0f - wx1, wy0 = 1.0f - wy1;
    int x0 = (int)x0f, y0 = (int)y0f;
    int x1 = x0 + 1,  y1 = y0 + 1;

    float vx0 = (x0 >= 0 && x0 <= W - 1) ? 1.0f : 0.0f;
    float vx1 = (x1 >= 0 && x1 <= W - 1) ? 1.0f : 0.0f;
    float vy0 = (y0 >= 0 && y0 <= H - 1) ? 1.0f : 0.0f;
    float vy1 = (y1 >= 0 && y1 <= H - 1) ? 1.0f : 0.0f;

    Cand cd;
    cd.w00 = wx0 * wy0 * vx0 * vy0;
    cd.w01 = wx1 * wy0 * vx1 * vy0;
    cd.w10 = wx0 * wy1 * vx0 * vy1;
    cd.w11 = wx1 * wy1 * vx1 * vy1;

    int xi0 = min(max(x0, 0), W - 1), xi1 = min(max(x1, 0), W - 1);
    int yi0 = min(max(y0, 0), H - 1), yi1 = min(max(y1, 0), H - 1);
    cd.c00 = (yi0 * W + xi0) * 8;     // float4 index of 128B record base
    cd.c01 = (yi0 * W + xi1) * 8;
    cd.c10 = (yi1 * W + xi0) * 8;
    cd.c11 = (yi1 * W + xi1) * 8;
    return cd;
}

// component select with compile-time j (folds to a plain register use)
#define F4AT(v, j) ((j) == 0 ? (v).x : (j) == 1 ? (v).y : (j) == 2 ? (v).z : (v).w)

// Per-lane channel set: {4q..4q+3} (line 0 of record) U {16+4q..16+4q+3}
// (line 1). P[2i] holds the line-0 quad, P[2i+1] the line-1 quad of corner i.
#define LOADSET(P, cd)                                           \
    do {                                                         \
        P[0] = rb[(cd).c00 + q];  P[1] = rb[(cd).c00 + 4 + q];   \
        P[2] = rb[(cd).c01 + q];  P[3] = rb[(cd).c01 + 4 + q];   \
        P[4] = rb[(cd).c10 + q];  P[5] = rb[(cd).c10 + 4 + q];   \
        P[6] = rb[(cd).c11 + q];  P[7] = rb[(cd).c11 + 4 + q];   \
    } while (0)

// j=0..3 -> line-0 quad (lf[0..3] = ch 4q+j); j=4..7 -> line-1 quad
// (lf[4..7] = ch 16+4q+j). Matches LOADSET's register layout exactly.
#define CONSUME(P, WT, kk)                                       \
    do {                                                         \
        float acc = 0.0f;                                        \
        _Pragma("unroll")                                        \
        for (int j = 0; j < 8; ++j) {                            \
            float a = F4AT(P[(j >> 2)],     j & 3);              \
            float b = F4AT(P[2 + (j >> 2)], j & 3);              \
            float d = F4AT(P[4 + (j >> 2)], j & 3);              \
            float e = F4AT(P[6 + (j >> 2)], j & 3);              \
            float g = WT.w00 * a + WT.w01 * b                    \
                    + WT.w10 * d + WT.w11 * e;                   \
            acc += fabsf(lf[j] - g);                             \
        }                                                        \
        acc += __shfl_xor(acc, 1);                               \
        acc += __shfl_xor(acc, 2);                               \
        s[kk] = acc * (-TEMP / (float)C);                        \
    } while (0)

// -------- main: 4 lanes/pixel, 8 ch each, f32 HWC, 2-deep k-pipeline ------
// Round-5 lesson: without a scheduling fence the compiler sinks each load
// next to its use (VGPR stayed at 68 -> ping-pong collapsed). The
// sched_barrier(0) between LOADSET(k+1) and CONSUME(k) pins program order:
// all 8 next-candidate loads are ISSUED before the current blend waits,
// keeping 8 gathers in flight under every blend phase.
__global__ __launch_bounds__(256, 3) void disp_kernel_hwc(
    const float* __restrict__ lchw, const float* __restrict__ rhwc,
    const float* __restrict__ offx, const float* __restrict__ offy,
    float* __restrict__ out)
{
    const int tid = threadIdx.x;
    const int q = tid & 3;                        // channel quarter
    const int p = blockIdx.x * 64 + (tid >> 2);   // pixel id
    const int w = p & (W - 1);
    const int h = p >> 9;

    // left features matching the per-lane channel set (round-1 proven map)
    float lf[8];
    #pragma unroll
    for (int j = 0; j < 4; ++j) lf[j]     = lchw[(q * 4 + j) * HW + p];
    #pragma unroll
    for (int j = 0; j < 4; ++j) lf[4 + j] = lchw[(16 + q * 4 + j) * HW + p];

    float okx[K], oky[K];
    #pragma unroll
    for (int k = 0; k < K; ++k) {
        okx[k] = offx[k * HW + p];
        oky[k] = offy[k * HW + p];
    }

    const float lx = (float)w;
    const float ly = (float)h;   // ref clips y to W-1: no-op (H <= W)
    const float4* rb = (const float4*)rhwc;   // 8 float4 per pixel

    float s[K];
    float4 P0[8], P1[8];        // ping-pong corner register sets
    Cand   W0, W1;

    W0 = cand_calc(lx, ly, okx[0], oky[0]);   // prologue: issue k=0
    LOADSET(P0, W0);

    #pragma unroll
    for (int k = 0; k < K; ++k) {
        if (k + 1 < K) {                      // issue k+1 into other set
            if ((k & 1) == 0) {
                W1 = cand_calc(lx, ly, okx[k + 1], oky[k + 1]);
                LOADSET(P1, W1);
            } else {
                W0 = cand_calc(lx, ly, okx[k + 1], oky[k + 1]);
                LOADSET(P0, W0);
            }
        }
        // fence: next-set loads may NOT sink below the current consume
        __builtin_amdgcn_sched_barrier(0);
        // consume current parity (its weights were NOT overwritten above)
        if ((k & 1) == 0) CONSUME(P0, W0, k); else CONSUME(P1, W1, k);
    }

    // softmax over K (redundant in all 4 lanes; lane q==0 writes)
    float m = s[0];
    #pragma unroll
    for (int k = 1; k < K; ++k) m = fmaxf(m, s[k]);
    float den = 0.0f, sx = 0.0f, sy = 0.0f;
    #pragma unroll
    for (int k = 0; k < K; ++k) {
        float e = __expf(s[k] - m);
        den += e;
        sx += okx[k] * e;
        sy += oky[k] * e;
    }
    float inv = 1.0f / den;
    if (q == 0) {
        out[p]      = sx * inv;
        out[HW + p] = sy * inv;
    }
}

// -------- fallback (round-1 kernel) if workspace too small ----------------
__global__ __launch_bounds__(256) void disp_kernel_chw(
    const float* __restrict__ left, const float* __restrict__ right,
    const float* __restrict__ offx, const float* __restrict__ offy,
    float* __restrict__ out)
{
    const int p = blockIdx.x * 256 + threadIdx.x;
    const int w = p & (W - 1);
    const int h = p >> 9;
    float lf[C];
    #pragma unroll
    for (int c = 0; c < C; ++c) lf[c] = left[c * HW + p];
    const float lx = (float)w, ly = (float)h;
    float s[K], okx[K], oky[K];
    #pragma unroll
    for (int k = 0; k < K; ++k) {
        const float ox = offx[k * HW + p], oy = offy[k * HW + p];
        okx[k] = ox; oky[k] = oy;
        Cand cd = cand_calc(lx, ly, ox, oy);
        int i00 = cd.c00 >> 3, i01 = cd.c01 >> 3;
        int i10 = cd.c10 >> 3, i11 = cd.c11 >> 3;
        float acc = 0.0f;
        #pragma unroll
        for (int c = 0; c < C; ++c) {
            const float* rc = right + c * HW;
            acc += fabsf(lf[c] - (cd.w00 * rc[i00] + cd.w01 * rc[i01]
                                + cd.w10 * rc[i10] + cd.w11 * rc[i11]));
        }
        s[k] = acc * (-TEMP / (float)C);
    }
    float m = s[0];
    #pragma unroll
    for (int k = 1; k < K; ++k) m = fmaxf(m, s[k]);
    float den = 0.0f, sx = 0.0f, sy = 0.0f;
    #pragma unroll
    for (int k = 0; k < K; ++k) {
        float e = __expf(s[k] - m);
        den += e; sx += okx[k] * e; sy += oky[k] * e;
    }
    float inv = 1.0f / den;
    out[p] = sx * inv;
    out[HW + p] = sy * inv;
}

extern "C" void kernel_launch(void* const* d_in, const int* in_sizes, int n_in,
                              void* d_out, int out_size, void* d_ws, size_t ws_size,
                              hipStream_t stream) {
    const float* left  = (const float*)d_in[0];
    const float* right = (const float*)d_in[1];
    const float* offx  = (const float*)d_in[2];
    const float* offy  = (const float*)d_in[3];
    float* out = (float*)d_out;

    const size_t need = (size_t)HW * C * sizeof(float);   // 16 MB
    if (ws_size >= need) {
        float* rhwc = (float*)d_ws;
        conv_right_hwc<<<HW / 128, 256, 0, stream>>>(right, rhwc);
        disp_kernel_hwc<<<HW / 64, 256, 0, stream>>>(left, rhwc, offx, offy, out);
    } else {
        disp_kernel_chw<<<HW / 256, 256, 0, stream>>>(left, right, offx, offy, out);
    }
}